// Round 5
// baseline (520.850 us; speedup 1.0000x reference)
//
#include <hip/hip_runtime.h>
#include <hip/hip_bf16.h>
#include <math.h>

#define NN 25000
#define NE 250000
#define DD 64
#define HH 4
#define NGROUP (NE / 16)   // 15625 16-edge groups

typedef __attribute__((ext_vector_type(8))) short bf16x8;
typedef __attribute__((ext_vector_type(4))) float f32x4;

#define WT_LD 136   // 128 + 8 pad (shorts) -> 272B row stride, 2-way LDS conflict (free)

__device__ __forceinline__ float softplus_f(float x) {
    return fmaxf(x, 0.0f) + __logf(1.0f + __expf(-fabsf(x)));
}

__device__ __forceinline__ unsigned short f2bf(float f) {
    __hip_bfloat16 h = __float2bfloat16(f);
    unsigned short u;
    __builtin_memcpy(&u, &h, 2);
    return u;
}

__device__ __forceinline__ float bf2f(unsigned short u) {
    return __uint_as_float(((unsigned int)u) << 16);
}

// Load 8 consecutive floats, split each into bf16 hi + bf16 lo (compensated).
__device__ __forceinline__ void load8(const float* p, bf16x8& hi, bf16x8& lo) {
    float4 a = *(const float4*)p;
    float4 b = *(const float4*)(p + 4);
    float v[8] = {a.x, a.y, a.z, a.w, b.x, b.y, b.z, b.w};
#pragma unroll
    for (int i = 0; i < 8; ++i) {
        unsigned short h = f2bf(v[i]);
        hi[i] = (short)h;
        lo[i] = (short)f2bf(v[i] - bf2f(h));
    }
}

// One wave = 16 edges, mfma_f32_16x16x32_bf16, A gathered straight into lanes,
// W^T bf16 in LDS (one copy shared by 8 waves of the 512-thread block).
// LDS 71680B -> 2 blocks/CU; grid MUST be 512 (2 blocks x 256 CUs): round 4
// launched 256 blocks -> 1 block/CU -> occupancy stuck at 22%.
// NOTE: body needs 128 VGPRs (32 f32x4 acc + 12 A frags). __launch_bounds__
// min-waves MUST stay at 2: (512,4) forces 64 VGPRs -> ~560MB scratch spill.
__global__ __launch_bounds__(512, 2)
void k_edge(const float* __restrict__ x, const float* __restrict__ ea,
            const float* __restrict__ W, const float* __restrict__ att,
            const float* __restrict__ bn_g, const float* __restrict__ bn_b,
            const float* __restrict__ bn_m, const float* __restrict__ bn_v,
            const int* __restrict__ eidx,
            unsigned short* __restrict__ outj,
            float* __restrict__ expa, float* __restrict__ denom)
{
    __shared__ unsigned short Wsh[256 * WT_LD];  // W^T bf16 [n][k], padded
    __shared__ float attI[256], attJ[256];

    const int tid = threadIdx.x;
    const int lane = tid & 63;
    const int q = lane >> 4;      // quad 0..3
    const int r = lane & 15;

    // Stage W^T (coalesced read of W[k*256+n], n fast-varying).
    for (int idx = tid; idx < 32768; idx += 512) {
        int k = idx >> 8, n = idx & 255;
        Wsh[n * WT_LD + k] = f2bf(W[idx]);
    }
    if (tid < 256) {
        int c = tid;
        attI[c] = att[(c >> 6) * 128 + (c & 63)];
        attJ[c] = att[(c >> 6) * 128 + 64 + (c & 63)];
    }
    float bnsc[HH], bnsh[HH];
#pragma unroll
    for (int t = 0; t < HH; ++t) {
        float inv = rsqrtf(bn_v[t] + 1e-5f);
        bnsc[t] = bn_g[t] * inv;
        bnsh[t] = bn_b[t] - bn_m[t] * bn_g[t] * inv;
    }
    __syncthreads();

    const int gw = blockIdx.x * 8 + (tid >> 6);
    const int nw = gridDim.x * 8;

    for (int g = gw; g < NGROUP; g += nw) {
        const int e0 = g * 16;
        const int ei = eidx[e0 + r];
        const int ej = eidx[NE + e0 + r];
        const float* xi = x + (size_t)ei * DD;
        const float* xj = x + (size_t)ej * DD;
        const float* ev = ea + (size_t)(e0 + r) * DD;

        bf16x8 Ahi[6], Alo[6];  // 0,1: x_i k-tiles; 2,3: x_j; 4,5: ea
        load8(xi + q * 8,      Ahi[0], Alo[0]);
        load8(xi + 32 + q * 8, Ahi[1], Alo[1]);
        load8(xj + q * 8,      Ahi[2], Alo[2]);
        load8(xj + 32 + q * 8, Ahi[3], Alo[3]);
        load8(ev + q * 8,      Ahi[4], Alo[4]);
        load8(ev + 32 + q * 8, Ahi[5], Alo[5]);

        f32x4 aci[16], acj[16];
#pragma unroll
        for (int nt = 0; nt < 16; ++nt) {
            aci[nt] = (f32x4){0.f, 0.f, 0.f, 0.f};
            acj[nt] = (f32x4){0.f, 0.f, 0.f, 0.f};
        }

        // ---- MFMA K-loop: 16 col-tiles x 4 k-tiles, hi+lo compensated A ----
#pragma unroll
        for (int nt = 0; nt < 16; ++nt) {
            const unsigned short* bp = &Wsh[(nt * 16 + r) * WT_LD + q * 8];
#pragma unroll
            for (int kt = 0; kt < 4; ++kt) {
                bf16x8 bf = *(const bf16x8*)(bp + kt * 32);
                const int fi = (kt < 2) ? kt : kt + 2;  // x_i, x_i, ea, ea
                const int fj = kt + 2;                  // x_j, x_j, ea, ea
                aci[nt] = __builtin_amdgcn_mfma_f32_16x16x32_bf16(Ahi[fi], bf, aci[nt], 0, 0, 0);
                aci[nt] = __builtin_amdgcn_mfma_f32_16x16x32_bf16(Alo[fi], bf, aci[nt], 0, 0, 0);
                acj[nt] = __builtin_amdgcn_mfma_f32_16x16x32_bf16(Ahi[fj], bf, acj[nt], 0, 0, 0);
                acj[nt] = __builtin_amdgcn_mfma_f32_16x16x32_bf16(Alo[fj], bf, acj[nt], 0, 0, 0);
            }
        }

        // ---- epilogue ----
        // C layout: col = nt*16 + r, row(edge-local) = q*4 + reg.
        float lg[4][4];  // [reg][head]
#pragma unroll
        for (int a = 0; a < 4; ++a)
#pragma unroll
            for (int b = 0; b < 4; ++b) lg[a][b] = 0.f;

#pragma unroll
        for (int nt = 0; nt < 16; ++nt) {
            const float ai = attI[nt * 16 + r];
            const float aj = attJ[nt * 16 + r];
            const int h = nt >> 2;
#pragma unroll
            for (int reg = 0; reg < 4; ++reg) {
                float spi = softplus_f(aci[nt][reg]);
                float spj = softplus_f(acj[nt][reg]);
                acj[nt][reg] = spj;  // keep post-softplus out_j
                lg[reg][h] += spi * ai + spj * aj;
            }
        }
#pragma unroll
        for (int off = 1; off < 16; off <<= 1) {
#pragma unroll
            for (int a = 0; a < 4; ++a)
#pragma unroll
                for (int b = 0; b < 4; ++b)
                    lg[a][b] += __shfl_xor(lg[a][b], off, 64);
        }
        float exv[4][4];
#pragma unroll
        for (int reg = 0; reg < 4; ++reg)
#pragma unroll
            for (int h = 0; h < 4; ++h)
                exv[reg][h] = __expf(softplus_f(fmaf(lg[reg][h], bnsc[h], bnsh[h])));

        if (r < 4) {  // lane r handles head r for its quad's 4 edges
#pragma unroll
            for (int reg = 0; reg < 4; ++reg) {
                const int e = e0 + q * 4 + reg;
                const int ii = eidx[e];
                expa[e * 4 + r] = exv[reg][r];
                atomicAdd(&denom[ii * 4 + r], exv[reg][r]);
            }
        }
        // out_j bf16 store, layout [e][d][h]: offset e*256 + d*4 + h
#pragma unroll
        for (int reg = 0; reg < 4; ++reg) {
            const unsigned e = (unsigned)(e0 + q * 4 + reg);
#pragma unroll
            for (int dt = 0; dt < 4; ++dt) {
                ushort4 pk;
                pk.x = f2bf(acj[dt][reg]);
                pk.y = f2bf(acj[4 + dt][reg]);
                pk.z = f2bf(acj[8 + dt][reg]);
                pk.w = f2bf(acj[12 + dt][reg]);
                *(ushort4*)&outj[e * 256 + (dt * 16 + r) * 4] = pk;
            }
        }
    }
}

// One wave per edge; lane = output dim d. Mean over heads folded in (0.25).
__global__ __launch_bounds__(256)
void k_scatter(const int* __restrict__ eidx,
               const unsigned short* __restrict__ outj,
               const float* __restrict__ expa,
               const float* __restrict__ denom,
               float* __restrict__ acc)
{
    const int e = blockIdx.x * 4 + (threadIdx.x >> 6);
    const int lane = threadIdx.x & 63;
    const int i = eidx[e];
    float4 ev = *(const float4*)&expa[e * 4];
    float4 dv = *(const float4*)&denom[i * 4];
    float w0 = 0.25f * ev.x / dv.x;
    float w1 = 0.25f * ev.y / dv.y;
    float w2 = 0.25f * ev.z / dv.z;
    float w3 = 0.25f * ev.w / dv.w;
    ushort4 v = *(const ushort4*)&outj[((unsigned)e << 8) | (lane << 2)];
    float s = w0 * bf2f(v.x) + w1 * bf2f(v.y) + w2 * bf2f(v.z) + w3 * bf2f(v.w);
    atomicAdd(&acc[i * DD + lane], s);
}

__global__ __launch_bounds__(256)
void k_final(const float* __restrict__ acc, const float* __restrict__ bias,
             float* __restrict__ out)
{
    const int t = blockIdx.x * 256 + threadIdx.x;
    out[t] = acc[t] + bias[t & 63];
}

extern "C" void kernel_launch(void* const* d_in, const int* in_sizes, int n_in,
                              void* d_out, int out_size, void* d_ws, size_t ws_size,
                              hipStream_t stream)
{
    (void)in_sizes; (void)n_in; (void)out_size; (void)ws_size;
    const float* x    = (const float*)d_in[0];
    const float* ea   = (const float*)d_in[1];
    const float* W    = (const float*)d_in[2];
    const float* att  = (const float*)d_in[3];
    const float* bias = (const float*)d_in[4];
    const float* bn_g = (const float*)d_in[5];
    const float* bn_b = (const float*)d_in[6];
    const float* bn_m = (const float*)d_in[7];
    const float* bn_v = (const float*)d_in[8];
    const int*   eidx = (const int*)d_in[9];
    float* out = (float*)d_out;

    // ws layout: outj bf16 [E][64][4] (128 MB) | expa f32 [E][4] | denom f32 [N][4] | acc f32 [N][64]
    char* ws = (char*)d_ws;
    unsigned short* outj = (unsigned short*)ws;
    float* expa  = (float*)(ws + (size_t)NE * 256 * 2);
    float* denom = (float*)(ws + (size_t)NE * 256 * 2 + (size_t)NE * 16);
    float* acc   = denom + (size_t)NN * 4;

    hipMemsetAsync(denom, 0, (size_t)(NN * 4 + NN * DD) * sizeof(float), stream);

    k_edge<<<dim3(512), dim3(512), 0, stream>>>(
        x, ea, W, att, bn_g, bn_b, bn_m, bn_v, eidx, outj, expa, denom);
    k_scatter<<<dim3(NE / 4), dim3(256), 0, stream>>>(eidx, outj, expa, denom, acc);
    k_final<<<dim3((NN * DD) / 256), dim3(256), 0, stream>>>(acc, bias, out);
}

// Round 6
// 303.965 us; speedup vs baseline: 1.7135x; 1.7135x over previous
//
#include <hip/hip_runtime.h>
#include <hip/hip_bf16.h>
#include <math.h>

#define NN 25000
#define NE 250000
#define DD 64
#define HH 4
#define NGROUP (NE / 16)   // 15625 16-edge groups

typedef __attribute__((ext_vector_type(8))) short bf16x8;
typedef __attribute__((ext_vector_type(4))) float f32x4;

#define WT_LD 136   // 128 + 8 pad (shorts) -> 272B row stride, 2-way LDS conflict (free)

__device__ __forceinline__ float softplus_f(float x) {
    return fmaxf(x, 0.0f) + __logf(1.0f + __expf(-fabsf(x)));
}

__device__ __forceinline__ unsigned short f2bf(float f) {
    __hip_bfloat16 h = __float2bfloat16(f);
    unsigned short u;
    __builtin_memcpy(&u, &h, 2);
    return u;
}

__device__ __forceinline__ float bf2f(unsigned short u) {
    return __uint_as_float(((unsigned int)u) << 16);
}

// Load 8 consecutive floats, split each into bf16 hi + bf16 lo (compensated).
__device__ __forceinline__ void load8(const float* p, bf16x8& hi, bf16x8& lo) {
    float4 a = *(const float4*)p;
    float4 b = *(const float4*)(p + 4);
    float v[8] = {a.x, a.y, a.z, a.w, b.x, b.y, b.z, b.w};
#pragma unroll
    for (int i = 0; i < 8; ++i) {
        unsigned short h = f2bf(v[i]);
        hi[i] = (short)h;
        lo[i] = (short)f2bf(v[i] - bf2f(h));
    }
}

// One wave = 16 edges, mfma_f32_16x16x32_bf16, A gathered straight into lanes,
// W^T bf16 in LDS (one copy shared by the block's 8 waves).
// OCCUPANCY NOTE (r5 lesson): gfx950 has a UNIFIED VGPR/AGPR file; the old
// structure kept 32 f32x4 accumulators live (128 acc regs) + 128 arch VGPRs
// = 256/thread -> hard cap 8 waves/CU (22% meas) no matter the launch shape.
// Fix: iterate nt=0..3, each iteration computes col-tiles {nt,nt+4,nt+8,nt+12}
// (one per head = exactly one ushort4 outj store) and consumes them
// immediately -> only 8 f32x4 acc live. Total ~110 regs -> (512,4) = 128-reg
// cap is now safe -> 2 blocks/CU x 8 waves = 16 waves/CU.
__global__ __launch_bounds__(512, 4)
void k_edge(const float* __restrict__ x, const float* __restrict__ ea,
            const float* __restrict__ W, const float* __restrict__ att,
            const float* __restrict__ bn_g, const float* __restrict__ bn_b,
            const float* __restrict__ bn_m, const float* __restrict__ bn_v,
            const int* __restrict__ eidx,
            unsigned short* __restrict__ outj,
            float* __restrict__ expa, float* __restrict__ denom)
{
    __shared__ unsigned short Wsh[256 * WT_LD];  // W^T bf16 [n][k], padded
    __shared__ float attI[256], attJ[256];

    const int tid = threadIdx.x;
    const int lane = tid & 63;
    const int q = lane >> 4;      // quad 0..3
    const int r = lane & 15;

    // Stage W^T (coalesced read of W[k*256+n], n fast-varying).
    for (int idx = tid; idx < 32768; idx += 512) {
        int k = idx >> 8, n = idx & 255;
        Wsh[n * WT_LD + k] = f2bf(W[idx]);
    }
    if (tid < 256) {
        int c = tid;
        attI[c] = att[(c >> 6) * 128 + (c & 63)];
        attJ[c] = att[(c >> 6) * 128 + 64 + (c & 63)];
    }
    float bnsc[HH], bnsh[HH];
#pragma unroll
    for (int t = 0; t < HH; ++t) {
        float inv = rsqrtf(bn_v[t] + 1e-5f);
        bnsc[t] = bn_g[t] * inv;
        bnsh[t] = bn_b[t] - bn_m[t] * bn_g[t] * inv;
    }
    __syncthreads();

    const int gw = blockIdx.x * 8 + (tid >> 6);
    const int nw = gridDim.x * 8;

    for (int g = gw; g < NGROUP; g += nw) {
        const int e0 = g * 16;
        const int ei = eidx[e0 + r];
        const int ej = eidx[NE + e0 + r];
        const float* xi = x + (size_t)ei * DD;
        const float* xj = x + (size_t)ej * DD;
        const float* ev = ea + (size_t)(e0 + r) * DD;

        bf16x8 Ahi[6], Alo[6];  // 0,1: x_i k-tiles; 2,3: x_j; 4,5: ea
        load8(xi + q * 8,      Ahi[0], Alo[0]);
        load8(xi + 32 + q * 8, Ahi[1], Alo[1]);
        load8(xj + q * 8,      Ahi[2], Alo[2]);
        load8(xj + 32 + q * 8, Ahi[3], Alo[3]);
        load8(ev + q * 8,      Ahi[4], Alo[4]);
        load8(ev + 32 + q * 8, Ahi[5], Alo[5]);

        float lg[4][4];  // [reg][head]
#pragma unroll
        for (int a = 0; a < 4; ++a)
#pragma unroll
            for (int b = 0; b < 4; ++b) lg[a][b] = 0.f;

        // ---- fused MFMA + epilogue: iteration nt handles col-tiles
        // {nt+4h | h=0..3} (one col per head per lane -> one ushort4 store) ----
#pragma unroll
        for (int nt = 0; nt < 4; ++nt) {
            f32x4 ai[4], aj[4];
#pragma unroll
            for (int h = 0; h < 4; ++h) {
                ai[h] = (f32x4){0.f, 0.f, 0.f, 0.f};
                aj[h] = (f32x4){0.f, 0.f, 0.f, 0.f};
            }
#pragma unroll
            for (int h = 0; h < 4; ++h) {
                const unsigned short* bp = &Wsh[((nt + 4 * h) * 16 + r) * WT_LD + q * 8];
#pragma unroll
                for (int kt = 0; kt < 4; ++kt) {
                    bf16x8 bf = *(const bf16x8*)(bp + kt * 32);
                    const int fi = (kt < 2) ? kt : kt + 2;  // x_i, x_i, ea, ea
                    const int fj = kt + 2;                  // x_j, x_j, ea, ea
                    ai[h] = __builtin_amdgcn_mfma_f32_16x16x32_bf16(Ahi[fi], bf, ai[h], 0, 0, 0);
                    ai[h] = __builtin_amdgcn_mfma_f32_16x16x32_bf16(Alo[fi], bf, ai[h], 0, 0, 0);
                    aj[h] = __builtin_amdgcn_mfma_f32_16x16x32_bf16(Ahi[fj], bf, aj[h], 0, 0, 0);
                    aj[h] = __builtin_amdgcn_mfma_f32_16x16x32_bf16(Alo[fj], bf, aj[h], 0, 0, 0);
                }
            }
            // consume: softplus, att partials, pack+store outj (acc dies here)
            const int dbase = nt * 16 + r;   // dim index d for this lane
#pragma unroll
            for (int reg = 0; reg < 4; ++reg) {
                ushort4 pk;
                unsigned short* pkp = (unsigned short*)&pk;
#pragma unroll
                for (int h = 0; h < 4; ++h) {
                    const int c = dbase + 64 * h;
                    float spi = softplus_f(ai[h][reg]);
                    float spj = softplus_f(aj[h][reg]);
                    lg[reg][h] += spi * attI[c] + spj * attJ[c];
                    pkp[h] = f2bf(spj);
                }
                const unsigned e = (unsigned)(e0 + q * 4 + reg);
                *(ushort4*)&outj[e * 256 + dbase * 4] = pk;
            }
        }

        // ---- logit reduce + BN + exp + denom ----
#pragma unroll
        for (int off = 1; off < 16; off <<= 1) {
#pragma unroll
            for (int a = 0; a < 4; ++a)
#pragma unroll
                for (int b = 0; b < 4; ++b)
                    lg[a][b] += __shfl_xor(lg[a][b], off, 64);
        }
        float exv[4][4];
#pragma unroll
        for (int reg = 0; reg < 4; ++reg)
#pragma unroll
            for (int h = 0; h < 4; ++h)
                exv[reg][h] = __expf(softplus_f(fmaf(lg[reg][h], bnsc[h], bnsh[h])));

        if (r < 4) {  // lane r handles head r for its quad's 4 edges
#pragma unroll
            for (int reg = 0; reg < 4; ++reg) {
                const int e = e0 + q * 4 + reg;
                const int ii = eidx[e];
                expa[e * 4 + r] = exv[reg][r];
                atomicAdd(&denom[ii * 4 + r], exv[reg][r]);
            }
        }
    }
}

// One wave per edge; lane = output dim d. Mean over heads folded in (0.25).
__global__ __launch_bounds__(256)
void k_scatter(const int* __restrict__ eidx,
               const unsigned short* __restrict__ outj,
               const float* __restrict__ expa,
               const float* __restrict__ denom,
               float* __restrict__ acc)
{
    const int e = blockIdx.x * 4 + (threadIdx.x >> 6);
    const int lane = threadIdx.x & 63;
    const int i = eidx[e];
    float4 ev = *(const float4*)&expa[e * 4];
    float4 dv = *(const float4*)&denom[i * 4];
    float w0 = 0.25f * ev.x / dv.x;
    float w1 = 0.25f * ev.y / dv.y;
    float w2 = 0.25f * ev.z / dv.z;
    float w3 = 0.25f * ev.w / dv.w;
    ushort4 v = *(const ushort4*)&outj[((unsigned)e << 8) | (lane << 2)];
    float s = w0 * bf2f(v.x) + w1 * bf2f(v.y) + w2 * bf2f(v.z) + w3 * bf2f(v.w);
    atomicAdd(&acc[i * DD + lane], s);
}

__global__ __launch_bounds__(256)
void k_final(const float* __restrict__ acc, const float* __restrict__ bias,
             float* __restrict__ out)
{
    const int t = blockIdx.x * 256 + threadIdx.x;
    out[t] = acc[t] + bias[t & 63];
}

extern "C" void kernel_launch(void* const* d_in, const int* in_sizes, int n_in,
                              void* d_out, int out_size, void* d_ws, size_t ws_size,
                              hipStream_t stream)
{
    (void)in_sizes; (void)n_in; (void)out_size; (void)ws_size;
    const float* x    = (const float*)d_in[0];
    const float* ea   = (const float*)d_in[1];
    const float* W    = (const float*)d_in[2];
    const float* att  = (const float*)d_in[3];
    const float* bias = (const float*)d_in[4];
    const float* bn_g = (const float*)d_in[5];
    const float* bn_b = (const float*)d_in[6];
    const float* bn_m = (const float*)d_in[7];
    const float* bn_v = (const float*)d_in[8];
    const int*   eidx = (const int*)d_in[9];
    float* out = (float*)d_out;

    // ws layout: outj bf16 [E][64][4] (128 MB) | expa f32 [E][4] | denom f32 [N][4] | acc f32 [N][64]
    char* ws = (char*)d_ws;
    unsigned short* outj = (unsigned short*)ws;
    float* expa  = (float*)(ws + (size_t)NE * 256 * 2);
    float* denom = (float*)(ws + (size_t)NE * 256 * 2 + (size_t)NE * 16);
    float* acc   = denom + (size_t)NN * 4;

    hipMemsetAsync(denom, 0, (size_t)(NN * 4 + NN * DD) * sizeof(float), stream);

    k_edge<<<dim3(512), dim3(512), 0, stream>>>(
        x, ea, W, att, bn_g, bn_b, bn_m, bn_v, eidx, outj, expa, denom);
    k_scatter<<<dim3(NE / 4), dim3(256), 0, stream>>>(eidx, outj, expa, denom, acc);
    k_final<<<dim3((NN * DD) / 256), dim3(256), 0, stream>>>(acc, bias, out);
}